// Round 6
// baseline (97.103 us; speedup 1.0000x reference)
//
#include <hip/hip_runtime.h>

#define BB 4
#define NN 4096

typedef __attribute__((ext_vector_type(8))) short short8v;   // 8 bf16 = 4 VGPRs
typedef __attribute__((ext_vector_type(4))) short short4v;   // 4 bf16 = 2 VGPRs
typedef __attribute__((ext_vector_type(4))) float float4v;   // MFMA acc

__device__ __forceinline__ unsigned short f2bf_rn(float f) {
    unsigned u = __float_as_uint(f);
    u += 0x7FFFu + ((u >> 16) & 1u);          // round-to-nearest-even
    return (unsigned short)(u >> 16);
}

// ---------------------------------------------------------------------------
// Kernel 1: fused QKV projection — scalar-broadcast GEMM (the r2 structure,
// which measured <=15 us; the r3-r5 MFMA version regressed to ~40-48 us via
// divergent W loads + u16 fragment gathers). Thread t -> (n4 = 4 n's,
// og = 5 o-rows): per c-iter 1 ds_read_b128 + 5 broadcast ds_read_b32 feed
// 20 FMAs. Outputs in MFMA-friendly layouts:
//   Qt[b][n][8], Kt[b][n][8]  (16 B rows)
//   Vsw 1 KB chunks per (b,ct,nb): elem[lane*8+j] = V[ct*16+(lane&15)]
//       [nb*32+(lane>>4)*8+j]  -> attn's av load = base + lane*16B.
// ---------------------------------------------------------------------------
__global__ __launch_bounds__(256) void qkv_kernel(
    const float* __restrict__ x,
    const float* __restrict__ Wq, const float* __restrict__ Wk,
    const float* __restrict__ Wv,
    unsigned short* __restrict__ Qt, unsigned short* __restrict__ Kt,
    unsigned short* __restrict__ Vsw)
{
    __shared__ float xs[64][68];            // [c][n] fp32, pad 68
    __shared__ float wl[64][81];            // [c][o] transposed weights, pad 81
    __shared__ unsigned short Ot[80][72];   // [o][n] bf16 staging (144 B rows)

    const int t  = threadIdx.x;
    const int b  = blockIdx.y;
    const int n0 = blockIdx.x * 64;

    // ---- stage weights transposed: wl[c][o] = W(o,c)
    #pragma unroll
    for (int i = 0; i < 20; ++i) {
        int idx = t + 256 * i;               // 5120 = 80*64
        int r = idx >> 6, c = idx & 63;
        float w;
        if (r < 8)       w = Wq[r * 64 + c];
        else if (r < 16) w = Wk[(r - 8) * 64 + c];
        else             w = Wv[(r - 16) * 64 + c];
        wl[c][r] = w;
    }
    // ---- stage x tile fp32, float4
    #pragma unroll
    for (int i = 0; i < 4; ++i) {
        int idx = t + 256 * i;               // 1024 float4 slots
        int c = idx >> 4, n4 = (idx & 15) * 4;
        *(float4*)&xs[c][n4] = *(const float4*)&x[(size_t)(b * 64 + c) * NN + n0 + n4];
    }
    __syncthreads();

    const int n4 = (t & 15) * 4;             // this thread's 4 n's
    const int og = t >> 4;                   // 0..15 -> o rows og*5..og*5+4

    float acc[5][4];
    #pragma unroll
    for (int k = 0; k < 5; ++k)
        #pragma unroll
        for (int i = 0; i < 4; ++i) acc[k][i] = 0.f;

    for (int c = 0; c < 64; ++c) {
        float4 xv = *(const float4*)&xs[c][n4];
        #pragma unroll
        for (int k = 0; k < 5; ++k) {
            float wv = wl[c][og * 5 + k];
            acc[k][0] += wv * xv.x;
            acc[k][1] += wv * xv.y;
            acc[k][2] += wv * xv.z;
            acc[k][3] += wv * xv.w;
        }
    }

    // ---- stage all 80 output rows as bf16
    #pragma unroll
    for (int k = 0; k < 5; ++k) {
        short4v pk;
        #pragma unroll
        for (int i = 0; i < 4; ++i) pk[i] = (short)f2bf_rn(acc[k][i]);
        *(short4v*)&Ot[og * 5 + k][n4] = pk;
    }
    __syncthreads();

    // ---- Qt/Kt writer: rows 0..7 / 8..15, 16 B per n, coalesced
    if (t < 128) {
        int n = t & 63;
        int rbase = (t < 64) ? 0 : 8;
        short8v p;
        #pragma unroll
        for (int j = 0; j < 8; ++j) p[j] = (short)Ot[rbase + j][n];
        unsigned short* dst = ((t < 64) ? Qt : Kt) + ((size_t)b * NN + n0 + n) * 8;
        *(short8v*)dst = p;
    }

    // ---- swizzled Vsw writer (V = Ot rows 16..79): 8 chunks of 1 KB
    {
        int ci = t >> 5, s = t & 31;
        int ct = ci >> 1, nbl = ci & 1;
        size_t nb = (size_t)blockIdx.x * 2 + nbl;
        unsigned short* cb = Vsw + ((size_t)(b * 4 + ct) * 128 + nb) * 512;
        #pragma unroll
        for (int h = 0; h < 2; ++h) {
            int l = s * 2 + h;
            short8v d = *(short8v*)&Ot[16 + ct * 16 + (l & 15)][nbl * 32 + ((l >> 4) << 3)];
            *(short8v*)(cb + l * 8) = d;
        }
    }
}

// ---------------------------------------------------------------------------
// Kernel 2: MFMA streaming attention, P-transpose pipelined one iteration.
// Block = 4 waves; block owns (b, 16-wide m-tile). Wave w owns n in
// [w*1024,(w+1)*1024), 32 chunks of 32 n. Per loop iter: scores for chunk
// i+1 (MFMA K=8-padded) -> exp -> pack -> Pb[buf^1], while PV consumes
// chunk i's P from Pb[buf] (LDS write completed a full iteration ago, so
// the ds_write->ds_read->MFMA latency is off the critical path). All global
// loads coalesced (swizzled V). No max-subtraction (logits <= ~3).
// ---------------------------------------------------------------------------
__global__ __launch_bounds__(256, 4) void attn_kernel(
    const unsigned short* __restrict__ Qt,
    const unsigned short* __restrict__ Kt,
    const unsigned short* __restrict__ Vsw,
    const float* __restrict__ x, const float* __restrict__ gamma,
    float* __restrict__ out)
{
    __shared__ __align__(16) unsigned short Pb[4][2][16][40]; // dbuf, 80 B rows
    __shared__ float Ored[4][64][17];
    __shared__ float Lred[4][16];
    __shared__ float Lf[16];

    const int t    = threadIdx.x;
    const int w    = t >> 6;
    const int lane = t & 63;
    const int quad = lane >> 4;
    const int l15  = lane & 15;
    const int b    = blockIdx.y;
    const int m0   = blockIdx.x * 16;

    const short8v zfrag = {0, 0, 0, 0, 0, 0, 0, 0};
    const float4v zacc  = {0.f, 0.f, 0.f, 0.f};

    // K-side (query-column) B fragment: B[k=c][m], quad0 holds real K
    short8v bk = zfrag;
    if (quad == 0)
        bk = *(const short8v*)(Kt + (size_t)(b * NN + m0 + l15) * 8);

    float4v acc[4];
    #pragma unroll
    for (int ct = 0; ct < 4; ++ct) acc[ct] = zacc;
    float Lacc = 0.f;

    const unsigned short* qrow = Qt + (size_t)(b * NN + w * 1024 + l15) * 8;
    const unsigned short* vptr = Vsw + ((size_t)b * 4 * 128 + w * 32) * 512 + lane * 8;

    // ---- prolog: chunk 0 scores -> Pb[w][0]; V chunk 0 into regs
    short8v av0 = *(const short8v*)(vptr);
    short8v av1 = *(const short8v*)(vptr + 1 * 128 * 512);
    short8v av2 = *(const short8v*)(vptr + 2 * 128 * 512);
    short8v av3 = *(const short8v*)(vptr + 3 * 128 * 512);
    {
        short8v aq0 = zfrag, aq1 = zfrag;
        if (quad == 0) {
            aq0 = *(const short8v*)(qrow);
            aq1 = *(const short8v*)(qrow + 16 * 8);
        }
        float4v s0 = __builtin_amdgcn_mfma_f32_16x16x32_bf16(aq0, bk, zacc, 0, 0, 0);
        float4v s1 = __builtin_amdgcn_mfma_f32_16x16x32_bf16(aq1, bk, zacc, 0, 0, 0);
        float p[8];
        #pragma unroll
        for (int j = 0; j < 4; ++j) p[j]     = __expf(s0[j]);
        #pragma unroll
        for (int j = 0; j < 4; ++j) p[4 + j] = __expf(s1[j]);
        #pragma unroll
        for (int j = 0; j < 8; ++j) Lacc += p[j];
        short4v pk0, pk1;
        #pragma unroll
        for (int j = 0; j < 4; ++j) {
            pk0[j] = (short)f2bf_rn(p[j]);
            pk1[j] = (short)f2bf_rn(p[4 + j]);
        }
        *(short4v*)&Pb[w][0][l15][quad * 4]      = pk0;
        *(short4v*)&Pb[w][0][l15][16 + quad * 4] = pk1;
    }

    for (int it = 0; it < 31; ++it) {
        const int itn = it + 1;

        // ---- V fragments for chunk itn (consumed next iter)
        short8v avn0 = *(const short8v*)(vptr + itn * 512);
        short8v avn1 = *(const short8v*)(vptr + 1 * 128 * 512 + itn * 512);
        short8v avn2 = *(const short8v*)(vptr + 2 * 128 * 512 + itn * 512);
        short8v avn3 = *(const short8v*)(vptr + 3 * 128 * 512 + itn * 512);

        // ---- scores for chunk itn -> Pb[w][itn&1]
        short8v aq0 = zfrag, aq1 = zfrag;
        if (quad == 0) {
            aq0 = *(const short8v*)(qrow + (size_t)(itn * 32) * 8);
            aq1 = *(const short8v*)(qrow + (size_t)(itn * 32 + 16) * 8);
        }
        float4v s0 = __builtin_amdgcn_mfma_f32_16x16x32_bf16(aq0, bk, zacc, 0, 0, 0);
        float4v s1 = __builtin_amdgcn_mfma_f32_16x16x32_bf16(aq1, bk, zacc, 0, 0, 0);
        float p[8];
        #pragma unroll
        for (int j = 0; j < 4; ++j) p[j]     = __expf(s0[j]);
        #pragma unroll
        for (int j = 0; j < 4; ++j) p[4 + j] = __expf(s1[j]);
        #pragma unroll
        for (int j = 0; j < 8; ++j) Lacc += p[j];
        short4v pk0, pk1;
        #pragma unroll
        for (int j = 0; j < 4; ++j) {
            pk0[j] = (short)f2bf_rn(p[j]);
            pk1[j] = (short)f2bf_rn(p[4 + j]);
        }
        *(short4v*)&Pb[w][itn & 1][l15][quad * 4]      = pk0;
        *(short4v*)&Pb[w][itn & 1][l15][16 + quad * 4] = pk1;

        // ---- PV for chunk it (P written a full iteration ago)
        short8v bp = *(const short8v*)&Pb[w][it & 1][l15][quad * 8];
        acc[0] = __builtin_amdgcn_mfma_f32_16x16x32_bf16(av0, bp, acc[0], 0, 0, 0);
        acc[1] = __builtin_amdgcn_mfma_f32_16x16x32_bf16(av1, bp, acc[1], 0, 0, 0);
        acc[2] = __builtin_amdgcn_mfma_f32_16x16x32_bf16(av2, bp, acc[2], 0, 0, 0);
        acc[3] = __builtin_amdgcn_mfma_f32_16x16x32_bf16(av3, bp, acc[3], 0, 0, 0);

        av0 = avn0; av1 = avn1; av2 = avn2; av3 = avn3;
    }

    // ---- epilog: PV for chunk 31
    {
        short8v bp = *(const short8v*)&Pb[w][1][l15][quad * 8];
        acc[0] = __builtin_amdgcn_mfma_f32_16x16x32_bf16(av0, bp, acc[0], 0, 0, 0);
        acc[1] = __builtin_amdgcn_mfma_f32_16x16x32_bf16(av1, bp, acc[1], 0, 0, 0);
        acc[2] = __builtin_amdgcn_mfma_f32_16x16x32_bf16(av2, bp, acc[2], 0, 0, 0);
        acc[3] = __builtin_amdgcn_mfma_f32_16x16x32_bf16(av3, bp, acc[3], 0, 0, 0);
    }

    // ---- combine quads' L partials within the wave
    Lacc += __shfl_xor(Lacc, 16, 64);
    Lacc += __shfl_xor(Lacc, 32, 64);
    if (lane < 16) Lred[w][lane] = Lacc;

    // ---- dump per-wave partial O: row c = ct*16 + quad*4 + r, col m = l15
    #pragma unroll
    for (int ct = 0; ct < 4; ++ct)
        #pragma unroll
        for (int r = 0; r < 4; ++r)
            Ored[w][ct * 16 + quad * 4 + r][l15] = acc[ct][r];
    __syncthreads();

    if (t < 16)
        Lf[t] = 1.f / (Lred[0][t] + Lred[1][t] + Lred[2][t] + Lred[3][t]);
    __syncthreads();

    // ---- vectorized epilogue: thread -> (c = t>>2, 4 consecutive m)
    {
        const float gv = gamma[0];
        int c = t >> 2, m4 = (t & 3) * 4;
        float4 o;
        #pragma unroll
        for (int i = 0; i < 4; ++i) {
            float s = Ored[0][c][m4 + i] + Ored[1][c][m4 + i]
                    + Ored[2][c][m4 + i] + Ored[3][c][m4 + i];
            ((float*)&o)[i] = s * Lf[m4 + i];
        }
        size_t gbase = (size_t)(b * 64 + c) * NN + m0 + m4;
        float4 xv = *(const float4*)&x[gbase];
        float4 r;
        r.x = gv * o.x + xv.x; r.y = gv * o.y + xv.y;
        r.z = gv * o.z + xv.z; r.w = gv * o.w + xv.w;
        *(float4*)&out[gbase] = r;
    }
}

extern "C" void kernel_launch(void* const* d_in, const int* in_sizes, int n_in,
                              void* d_out, int out_size, void* d_ws, size_t ws_size,
                              hipStream_t stream) {
    const float* x     = (const float*)d_in[0];
    const float* Wq    = (const float*)d_in[1];
    const float* Wk    = (const float*)d_in[2];
    const float* Wv    = (const float*)d_in[3];
    const float* gamma = (const float*)d_in[4];
    float* out = (float*)d_out;

    unsigned short* ws = (unsigned short*)d_ws;
    unsigned short* Qt  = ws;                        // [B][N][8]  bf16, 256 KB
    unsigned short* Kt  = Qt + (size_t)BB * NN * 8;  // [B][N][8]  bf16, 256 KB
    unsigned short* Vsw = Kt + (size_t)BB * NN * 8;  // [B][4][128][512] bf16, 2 MB

    qkv_kernel<<<dim3(NN / 64, BB), 256, 0, stream>>>(x, Wq, Wk, Wv, Qt, Kt, Vsw);
    attn_kernel<<<dim3(NN / 16, BB), 256, 0, stream>>>(Qt, Kt, Vsw, x, gamma, out);
}